// Round 12
// baseline (357.434 us; speedup 1.0000x reference)
//
#include <hip/hip_runtime.h>

// ---------------------------------------------------------------------------
// Pruned multi-head attention. fp32 I/O, split-bf16 (hi+lo) MFMA compute.
// B=2, S=2048, D_MODEL=1024, H=16, d_k=64, keep=int(2048*0.9)=1843
//
// Round 20: gemm_qkv retiled 128x128 -> 128x64 (grid 512 -> 1024 blocks =
// 4 blocks/CU; it was GRID-limited at 2 blocks/CU, not LDS/VGPR-limited).
// Same K-loop + accumulation order -> bit-identical output. W staging uses
// the proven gemm_v 64-row pattern; XCD remap extended over 1024 blocks
// (each XCD owns 8 complete A-row-panels). Everything else = R19.
// ---------------------------------------------------------------------------

typedef __attribute__((ext_vector_type(8))) short short8;   // 8 bf16 (4 VGPRs)
typedef __attribute__((ext_vector_type(4))) short short4v;
typedef __attribute__((ext_vector_type(4))) float f32x4;
typedef __attribute__((ext_vector_type(16))) float f32x16;
typedef __attribute__((ext_vector_type(4))) unsigned int u32x4;

#define KEEP 1843

#if __has_builtin(__builtin_amdgcn_exp2f)
  #define PEXP(x) __builtin_amdgcn_exp2f(x)
  #define QSC 0.18033688011112042f   // log2(e)/8 folded into Q projection
#else
  #define PEXP(x) __expf(x)
  #define QSC 0.125f
#endif

#define AS1(p) ((const __attribute__((address_space(1))) void*)(p))
#define AS3(p) ((__attribute__((address_space(3))) void*)(p))

static __device__ __forceinline__ float bf2f(unsigned short s) {
    union { unsigned u; float f; } v; v.u = ((unsigned)s) << 16; return v.f;
}
static __device__ __forceinline__ unsigned short f2bf(float f) {
    union { float f; unsigned u; } v; v.f = f;
    unsigned u = v.u;
    unsigned r = (u + 0x7FFFu + ((u >> 16) & 1u)) >> 16;   // RNE
    return (unsigned short)r;
}

#define MFMA(A, B, C)   __builtin_amdgcn_mfma_f32_16x16x32_bf16(A, B, C, 0, 0, 0)
#define MFMA32(A, B, C) __builtin_amdgcn_mfma_f32_32x32x16_bf16(A, B, C, 0, 0, 0)

// Fragment-major layout for Q and K (per bh, 131072 shorts):
//   (s,d) -> (s>>5)*2048 + (((d>>4)*2 + ((d>>3)&1))*32 + (s&31))*8 + (d&7)
// Fragment-major V layout (per bh):
//   (s,d) -> (s>>5)*2048 + ((((((s>>4)&1)*2 + (d>>5))*2 + ((s>>3)&1))*32) + (d&31))*8 + (s&7)

// All fp32->bf16(hi/lo) conversions + rowsum/colsum zeroing in one launch.
__global__ __launch_bounds__(256) void cvt_all(
    const float* __restrict__ q,  const float* __restrict__ k,
    const float* __restrict__ v,  const float* __restrict__ Wq,
    const float* __restrict__ Wk, const float* __restrict__ Wv,
    const float* __restrict__ Wo,
    unsigned short* __restrict__ qh, unsigned short* __restrict__ ql,
    unsigned short* __restrict__ kh, unsigned short* __restrict__ kl,
    unsigned short* __restrict__ vh,
    unsigned short* __restrict__ wqh, unsigned short* __restrict__ wql,
    unsigned short* __restrict__ wkh, unsigned short* __restrict__ wkl,
    unsigned short* __restrict__ wvh,
    unsigned short* __restrict__ woh, unsigned short* __restrict__ wol,
    float* __restrict__ zbuf)
{
    int g = blockIdx.x * 256 + threadIdx.x;      // [0, 4194304+32768)
    if (g >= 4194304) {                          // zero rowsum+colsum
        int idx = g - 4194304;                   // 32768 f32x4 groups
        ((f32x4*)zbuf)[idx] = (f32x4){0.f, 0.f, 0.f, 0.f};
        return;
    }
    const float* in; unsigned short* oh; unsigned short* ol; int idx;
    if (g < 3145728) {                           // activations: 3 x 2^20 groups
        int seg = g >> 20; idx = g & 1048575;
        if (seg == 0)      { in = q; oh = qh;  ol = ql;  }
        else if (seg == 1) { in = k; oh = kh;  ol = kl;  }
        else               { in = v; oh = vh;  ol = 0;   }
    } else {                                     // weights: 4 x 2^18 groups
        int gw = g - 3145728; int seg = gw >> 18; idx = gw & 262143;
        if (seg == 0)      { in = Wq; oh = wqh; ol = wql; }
        else if (seg == 1) { in = Wk; oh = wkh; ol = wkl; }
        else if (seg == 2) { in = Wv; oh = wvh; ol = 0;   }
        else               { in = Wo; oh = woh; ol = wol; }
    }
    f32x4 x = ((const f32x4*)in)[idx];
    short4v h, l;
#pragma unroll
    for (int j = 0; j < 4; j++) {
        unsigned short hv = f2bf(x[j]);
        h[j] = (short)hv;
        l[j] = (short)f2bf(x[j] - bf2f(hv));
    }
    ((short4v*)oh)[idx] = h;
    if (ol) ((short4v*)ol)[idx] = l;
}

// Fused Q/K projections (split hi+lo, 3-term), LDS-staged + swizzled.
// 128x64 tile, BK=32, 1024 blocks (4/CU). z=0: Q (scaled QSC); z=1: K.
// Both frag-major hi+lo. Same accumulation order as 128x128 -> bit-identical.
__global__ __launch_bounds__(256) void gemm_qkv(
    const short* __restrict__ A0, const short* __restrict__ Al0,
    const short* __restrict__ A1, const short* __restrict__ Al1,
    const short* __restrict__ W0, const short* __restrict__ Wl0,
    const short* __restrict__ W1, const short* __restrict__ Wl1,
    const float* __restrict__ b0, const float* __restrict__ b1,
    unsigned short* __restrict__ Qhi, unsigned short* __restrict__ Qlo,
    unsigned short* __restrict__ Khi, unsigned short* __restrict__ Klo)
{
    // XCD-chunked remap over 1024 blocks: each XCD owns 128 consecutive
    // tiles = 8 complete A-row-panels (16 col-tiles each).
    int lin = blockIdx.x + (blockIdx.y << 4) + (blockIdx.z << 9);   // [0,1024)
    int tile = (lin & 7) * 128 + (lin >> 3);
    int bx = tile & 15, by = (tile >> 4) & 31, bz = tile >> 9;

    const short *Ahg, *Alg, *Whg, *Wlg; const float* bias;
    unsigned short *oh, *ol; float scale;
    if (bz == 0) { Ahg=A0; Alg=Al0; Whg=W0; Wlg=Wl0; bias=b0; oh=Qhi; ol=Qlo; scale=QSC;  }
    else         { Ahg=A1; Alg=Al1; Whg=W1; Wlg=Wl1; bias=b1; oh=Khi; ol=Klo; scale=1.0f; }

    __shared__ __align__(16) short Ah_l[128*32];
    __shared__ __align__(16) short Al_l[128*32];
    __shared__ __align__(16) short Wh_l[64*32];
    __shared__ __align__(16) short Wl_l[64*32];

    int tid  = threadIdx.x;
    int w    = tid >> 6;
    int lane = tid & 63;
    int ln   = lane & 15;
    int quad = lane >> 4;
    int rowBase = by * 128;
    int colBase = bx * 64;
    int mBase = (w & 1) * 64;        // wave's quadrant: 64 rows x 32 cols
    int nBase = (w >> 1) * 32;

    int srow = (lane >> 2);
    int scol = (((lane & 3) ^ ((lane >> 3) & 3))) * 8;
    int cs = ((quad ^ ((ln >> 1) & 3))) * 8;

    const short* Ag_h = Ahg + (size_t)rowBase * 1024;
    const short* Ag_l = Alg + (size_t)rowBase * 1024;
    const short* Wg_h = Whg + (size_t)colBase * 1024;
    const short* Wg_l = Wlg + (size_t)colBase * 1024;

    f32x4 acc[4][2];
#pragma unroll
    for (int i = 0; i < 4; i++)
#pragma unroll
        for (int j = 0; j < 2; j++) acc[i][j] = (f32x4){0.f, 0.f, 0.f, 0.f};

    for (int kk = 0; kk < 1024; kk += 32) {
#pragma unroll
        for (int j = 0; j < 2; j++) {
            int r = w*32 + j*16;
            size_t go = (size_t)(r + srow) * 1024 + kk + scol;
            __builtin_amdgcn_global_load_lds(AS1(Ag_h + go), AS3(Ah_l + r*32), 16, 0, 0);
            __builtin_amdgcn_global_load_lds(AS1(Ag_l + go), AS3(Al_l + r*32), 16, 0, 0);
        }
        {
            int c = w * 16;   // wave stages 16 W-rows (64-row tile / 4 waves)
            size_t go = (size_t)(c + srow) * 1024 + kk + scol;
            __builtin_amdgcn_global_load_lds(AS1(Wg_h + go), AS3(Wh_l + c*32), 16, 0, 0);
            __builtin_amdgcn_global_load_lds(AS1(Wg_l + go), AS3(Wl_l + c*32), 16, 0, 0);
        }
        __syncthreads();

        short8 ah[4], al[4], bh[2], bl[2];
#pragma unroll
        for (int mt = 0; mt < 4; mt++) {
            int r = mBase + mt*16 + ln;
            ah[mt] = *(const short8*)(Ah_l + r*32 + cs);
            al[mt] = *(const short8*)(Al_l + r*32 + cs);
        }
#pragma unroll
        for (int nt = 0; nt < 2; nt++) {
            int c = nBase + nt*16 + ln;
            bh[nt] = *(const short8*)(Wh_l + c*32 + cs);
            bl[nt] = *(const short8*)(Wl_l + c*32 + cs);
        }
#pragma unroll
        for (int mt = 0; mt < 4; mt++)
#pragma unroll
            for (int nt = 0; nt < 2; nt++) {
                acc[mt][nt] = MFMA(ah[mt], bh[nt], acc[mt][nt]);
                acc[mt][nt] = MFMA(ah[mt], bl[nt], acc[mt][nt]);
                acc[mt][nt] = MFMA(al[mt], bh[nt], acc[mt][nt]);
            }
        __syncthreads();
    }

#pragma unroll
    for (int mt = 0; mt < 4; mt++) {
#pragma unroll
        for (int nt = 0; nt < 2; nt++) {
            int col = colBase + nBase + nt*16 + ln;
            float bv = bias[col];
#pragma unroll
            for (int i = 0; i < 4; i++) {
                int row = rowBase + mBase + mt*16 + quad*4 + i;   // D: row=quad*4+reg
                float val = (acc[mt][nt][i] + bv) * scale;
                int b_  = row >> 11, s = row & 2047;
                int h   = col >> 6,  d = col & 63;
                int bh_ = b_ * 16 + h;
                size_t idx = (size_t)bh_ * 131072 + (size_t)(s >> 5) * 2048
                    + ((size_t)(((d >> 4) * 2 + ((d >> 3) & 1)) * 32 + (s & 31))) * 8 + (d & 7);
                unsigned short hv = f2bf(val);
                oh[idx] = hv;
                ol[idx] = f2bf(val - bf2f(hv));
            }
        }
    }
}

// V projection, 1-term (hi x hi), 128x64 tile (512 blocks = 2/CU), with the
// prune mask fused into the epilogue (runs after topk_mask). Frag-major V.
__global__ __launch_bounds__(256) void gemm_v(
    const short* __restrict__ Ag, const short* __restrict__ Whg,
    const float* __restrict__ bias, const float* __restrict__ maskf,
    unsigned short* __restrict__ Vt)
{
    int lin = blockIdx.x + (blockIdx.y << 4);                  // [0,512)
    int tile = (lin & 7) * 64 + (lin >> 3);
    int bx = tile & 15, by = tile >> 4;

    __shared__ __align__(16) short A_l[128*32];
    __shared__ __align__(16) short Wh_l[64*32];

    int tid  = threadIdx.x;
    int w    = tid >> 6;
    int lane = tid & 63;
    int ln   = lane & 15;
    int quad = lane >> 4;
    int rowBase = by * 128;
    int colBase = bx * 64;
    int mBase = (w & 1) * 64;
    int nBase = (w >> 1) * 32;

    int srow = (lane >> 2);
    int scol = (((lane & 3) ^ ((lane >> 3) & 3))) * 8;
    int cs = ((quad ^ ((ln >> 1) & 3))) * 8;
    const short* Abase = Ag  + (size_t)rowBase * 1024;
    const short* Whb   = Whg + (size_t)colBase * 1024;

    f32x4 acc[4][2];
#pragma unroll
    for (int i = 0; i < 4; i++)
#pragma unroll
        for (int j = 0; j < 2; j++) acc[i][j] = (f32x4){0.f, 0.f, 0.f, 0.f};

    for (int kk = 0; kk < 1024; kk += 32) {
#pragma unroll
        for (int j = 0; j < 2; j++) {
            int r = w*32 + j*16;
            size_t go = (size_t)(r + srow) * 1024 + kk + scol;
            __builtin_amdgcn_global_load_lds(AS1(Abase + go), AS3(A_l + r*32), 16, 0, 0);
        }
        {
            int c = w * 16;   // wave stages 16 W-rows (64-row tile / 4 waves)
            size_t go = (size_t)(c + srow) * 1024 + kk + scol;
            __builtin_amdgcn_global_load_lds(AS1(Whb + go), AS3(Wh_l + c*32), 16, 0, 0);
        }
        __syncthreads();

        short8 a[4], bh2[2];
#pragma unroll
        for (int mt = 0; mt < 4; mt++)
            a[mt] = *(const short8*)(A_l + (mBase + mt*16 + ln)*32 + cs);
#pragma unroll
        for (int nt = 0; nt < 2; nt++)
            bh2[nt] = *(const short8*)(Wh_l + (nBase + nt*16 + ln)*32 + cs);
#pragma unroll
        for (int mt = 0; mt < 4; mt++)
#pragma unroll
            for (int nt = 0; nt < 2; nt++)
                acc[mt][nt] = MFMA(a[mt], bh2[nt], acc[mt][nt]);
        __syncthreads();
    }

#pragma unroll
    for (int mt = 0; mt < 4; mt++) {
#pragma unroll
        for (int nt = 0; nt < 2; nt++) {
            int col = colBase + nBase + nt*16 + ln;
            float bv = bias[col];
#pragma unroll
            for (int i = 0; i < 4; i++) {
                int row = rowBase + mBase + mt*16 + quad*4 + i;
                float val = acc[mt][nt][i] + bv;
                int b_  = row >> 11, s = row & 2047;
                int h   = col >> 6,  d = col & 63;
                int bh_ = b_ * 16 + h;
                val *= maskf[bh_ * 2048 + s];   // fused prune mask (0/1)
                size_t idx = (size_t)bh_ * 131072 + (size_t)(s >> 5) * 2048
                    + ((size_t)((((((s >> 4) & 1) * 2 + (d >> 5)) * 2 + ((s >> 3) & 1)) * 32)
                                + (d & 31))) * 8 + (s & 7);
                Vt[idx] = f2bf(val);
            }
        }
    }
}

// out = concat(bf16) @ Wo^T + bo (split Wo, fp32 out), 128x64 tile
// (512 blocks = 2/CU), LDS-staged + swizzled.
__global__ __launch_bounds__(256) void gemm_out(
    const short* __restrict__ Ag, const short* __restrict__ Whg,
    const short* __restrict__ Wlg, const float* __restrict__ bias,
    float* __restrict__ out)
{
    int lin = blockIdx.x + (blockIdx.y << 4);                  // [0,512)
    int tile = (lin & 7) * 64 + (lin >> 3);
    int bx = tile & 15, by = tile >> 4;

    __shared__ __align__(16) short A_l[128*32];
    __shared__ __align__(16) short Wh_l[64*32];
    __shared__ __align__(16) short Wl_l[64*32];

    int tid  = threadIdx.x;
    int w    = tid >> 6;
    int lane = tid & 63;
    int ln   = lane & 15;
    int quad = lane >> 4;
    int rowBase = by * 128;
    int colBase = bx * 64;
    int mBase = (w & 1) * 64;
    int nBase = (w >> 1) * 32;

    int srow = (lane >> 2);
    int scol = (((lane & 3) ^ ((lane >> 3) & 3))) * 8;
    int cs = ((quad ^ ((ln >> 1) & 3))) * 8;
    const short* Abase = Ag  + (size_t)rowBase * 1024;
    const short* Whb   = Whg + (size_t)colBase * 1024;
    const short* Wlb   = Wlg + (size_t)colBase * 1024;

    f32x4 acc[4][2];
#pragma unroll
    for (int i = 0; i < 4; i++)
#pragma unroll
        for (int j = 0; j < 2; j++) acc[i][j] = (f32x4){0.f, 0.f, 0.f, 0.f};

    for (int kk = 0; kk < 1024; kk += 32) {
#pragma unroll
        for (int j = 0; j < 2; j++) {
            int r = w*32 + j*16;
            size_t go = (size_t)(r + srow) * 1024 + kk + scol;
            __builtin_amdgcn_global_load_lds(AS1(Abase + go), AS3(A_l + r*32), 16, 0, 0);
        }
        {
            int c = w * 16;
            size_t go = (size_t)(c + srow) * 1024 + kk + scol;
            __builtin_amdgcn_global_load_lds(AS1(Whb + go), AS3(Wh_l + c*32), 16, 0, 0);
            __builtin_amdgcn_global_load_lds(AS1(Wlb + go), AS3(Wl_l + c*32), 16, 0, 0);
        }
        __syncthreads();

        short8 a[4], bh2[2], bl2[2];
#pragma unroll
        for (int mt = 0; mt < 4; mt++)
            a[mt] = *(const short8*)(A_l + (mBase + mt*16 + ln)*32 + cs);
#pragma unroll
        for (int nt = 0; nt < 2; nt++) {
            int c = nBase + nt*16 + ln;
            bh2[nt] = *(const short8*)(Wh_l + c*32 + cs);
            bl2[nt] = *(const short8*)(Wl_l + c*32 + cs);
        }
#pragma unroll
        for (int mt = 0; mt < 4; mt++)
#pragma unroll
            for (int nt = 0; nt < 2; nt++) {
                acc[mt][nt] = MFMA(a[mt], bh2[nt], acc[mt][nt]);
                acc[mt][nt] = MFMA(a[mt], bl2[nt], acc[mt][nt]);
            }
        __syncthreads();
    }

#pragma unroll
    for (int mt = 0; mt < 4; mt++) {
#pragma unroll
        for (int nt = 0; nt < 2; nt++) {
            int col = colBase + nBase + nt*16 + ln;
            float bv = bias[col];
#pragma unroll
            for (int i = 0; i < 4; i++) {
                int row = rowBase + mBase + mt*16 + quad*4 + i;
                out[(size_t)row * 1024 + col] = acc[mt][nt][i] + bv;
            }
        }
    }
}

// rowsum[q] += sum over this block's k-quarter of 2^(c_qk), HI-ONLY scores.
__global__ __launch_bounds__(256) void attn_rowsum(
    const short* __restrict__ Qhi, const short* __restrict__ Khi,
    float* __restrict__ rowsum)
{
    int bh = blockIdx.z, tid = threadIdx.x;
    int w = tid >> 6, lane = tid & 63, ln = lane & 15, quad = lane >> 4;
    int qb  = blockIdx.x * 256 + w * 64;
    int kt0 = blockIdx.y * 32;            // 32 k-tiles of 16 = 512 keys
    const short* QH = Qhi + (size_t)bh * 131072;
    const short* KH = Khi + (size_t)bh * 131072;

    short8 qh[4][2];
#pragma unroll
    for (int mt = 0; mt < 4; mt++)
#pragma unroll
        for (int half = 0; half < 2; half++) {
            size_t o = (size_t)((qb >> 5) + (mt >> 1)) * 2048
                     + (size_t)(half * 4 + quad) * 256 + ((mt & 1) * 16 + ln) * 8;
            qh[mt][half] = *(const short8*)(QH + o);
        }

    short8 kh[2][2];   // [buf][dchunk]
    auto loadK = [&](int buf, int kt) {
        size_t ko = (size_t)(kt >> 1) * 2048 + (size_t)quad * 256 + ((kt & 1) * 16 + ln) * 8;
        kh[buf][0] = *(const short8*)(KH + ko);
        kh[buf][1] = *(const short8*)(KH + ko + 1024);
    };

    float racc[4][4] = {};
    auto comp = [&](int buf) {
#pragma unroll
        for (int mt = 0; mt < 4; mt++) {
            f32x4 c1 = (f32x4){0.f,0.f,0.f,0.f};
            c1 = MFMA(qh[mt][0], kh[buf][0], c1);
            c1 = MFMA(qh[mt][1], kh[buf][1], c1);
#pragma unroll
            for (int i = 0; i < 4; i++)
                racc[mt][i] += PEXP(c1[i]);
        }
    };

    loadK(0, kt0);
    for (int t = 0; t < 32; t += 2) {
        loadK(1, kt0 + t + 1);
        comp(0);
        if (t + 2 < 32) loadK(0, kt0 + t + 2);
        comp(1);
    }
#pragma unroll
    for (int mt = 0; mt < 4; mt++)
#pragma unroll
        for (int i = 0; i < 4; i++)
            for (int d = 1; d < 16; d <<= 1)
                racc[mt][i] += __shfl_xor(racc[mt][i], d, 64);
    if (ln == 0) {
#pragma unroll
        for (int mt = 0; mt < 4; mt++)
#pragma unroll
            for (int i = 0; i < 4; i++)
                atomicAdd(&rowsum[bh * 2048 + qb + mt*16 + quad*4 + i], racc[mt][i]);
    }
}

// colsum[k] += sum over this block's q-quarter of 2^(c_qk)/rowsum[q].
// 3-term split (hi*hi + hi*lo + lo*hi) — feeds the top-k ranking, which
// needs per-score ~2^-17 precision (R17 proved hi-only flips the mask).
__global__ __launch_bounds__(256) void attn_colsum(
    const short* __restrict__ Qhi, const short* __restrict__ Qlo,
    const short* __restrict__ Khi, const short* __restrict__ Klo,
    const float* __restrict__ rowsum, float* __restrict__ colsum)
{
    __shared__ float sli[512];
    int bh = blockIdx.z, tid = threadIdx.x;
    int q0 = blockIdx.y * 512;
    for (int j = tid; j < 512; j += 256)
        sli[j] = 1.0f / rowsum[bh * 2048 + q0 + j];
    __syncthreads();

    int w = tid >> 6, lane = tid & 63, ln = lane & 15, quad = lane >> 4;
    int kb  = blockIdx.x * 256 + w * 64;
    int qt0 = blockIdx.y * 32;            // 32 q-tiles of 16
    const short* QH = Qhi + (size_t)bh * 131072;
    const short* QL = Qlo + (size_t)bh * 131072;
    const short* KH = Khi + (size_t)bh * 131072;
    const short* KL = Klo + (size_t)bh * 131072;

    short8 kh[4][2], kl[4][2];
#pragma unroll
    for (int nt = 0; nt < 4; nt++)
#pragma unroll
        for (int half = 0; half < 2; half++) {
            size_t o = (size_t)((kb >> 5) + (nt >> 1)) * 2048 + (size_t)half * 1024
                     + (size_t)quad * 256 + ((nt & 1) * 16 + ln) * 8;
            kh[nt][half] = *(const short8*)(KH + o);
            kl[nt][half] = *(const short8*)(KL + o);
        }

    short8 qh[2][2], ql[2][2];   // [buf][half]
    auto loadQ = [&](int buf, int qt) {
        int qtt = qt0 + qt;
        size_t base = (size_t)(qtt >> 1) * 2048 + ((qtt & 1) * 16 + ln) * 8;
        qh[buf][0] = *(const short8*)(QH + base + (size_t)quad * 256);
        qh[buf][1] = *(const short8*)(QH + base + (size_t)(4 + quad) * 256);
        ql[buf][0] = *(const short8*)(QL + base + (size_t)quad * 256);
        ql[buf][1] = *(const short8*)(QL + base + (size_t)(4 + quad) * 256);
    };

    float cacc[4] = {0.f, 0.f, 0.f, 0.f};
    auto comp = [&](int buf, int qt) {
#pragma unroll
        for (int nt = 0; nt < 4; nt++) {
            f32x4 c1 = (f32x4){0.f,0.f,0.f,0.f};
            f32x4 c2 = (f32x4){0.f,0.f,0.f,0.f};
            c1 = MFMA(qh[buf][0], kh[nt][0], c1); c1 = MFMA(qh[buf][1], kh[nt][1], c1);
            c2 = MFMA(qh[buf][0], kl[nt][0], c2); c2 = MFMA(qh[buf][1], kl[nt][1], c2);
            c2 = MFMA(ql[buf][0], kh[nt][0], c2); c2 = MFMA(ql[buf][1], kh[nt][1], c2);
#pragma unroll
            for (int i = 0; i < 4; i++) {
                int r = qt*16 + quad*4 + i;
                cacc[nt] += PEXP(c1[i] + c2[i]) * sli[r];
            }
        }
    };

    loadQ(0, 0);
    for (int qt = 0; qt < 32; qt += 2) {
        loadQ(1, qt + 1);
        comp(0, qt);
        if (qt + 2 < 32) loadQ(0, qt + 2);
        comp(1, qt + 1);
    }
#pragma unroll
    for (int nt = 0; nt < 4; nt++) {
        cacc[nt] += __shfl_xor(cacc[nt], 16, 64);
        cacc[nt] += __shfl_xor(cacc[nt], 32, 64);
        if (lane < 16) atomicAdd(&colsum[bh * 2048 + kb + nt*16 + lane], cacc[nt]);
    }
}

// Per (b,h): threshold = KEEP-th largest colsum via 4-level radix select.
// Parallel suffix-scan over the 256-bin histogram.
__global__ __launch_bounds__(256) void topk_mask(
    const float* __restrict__ colsum, float* __restrict__ maskf)
{
    __shared__ unsigned keys[2048];
    __shared__ int hist[256];
    __shared__ int suf[256];
    __shared__ unsigned sh_pref;
    __shared__ int sh_need;
    int bh = blockIdx.x, tid = threadIdx.x;
    for (int j = tid; j < 2048; j += 256) {
        unsigned u = __float_as_uint(colsum[bh * 2048 + j]);
        keys[j] = (u & 0x80000000u) ? ~u : (u | 0x80000000u);
    }
    if (tid == 0) { sh_pref = 0; sh_need = KEEP; }
    __syncthreads();
#pragma unroll
    for (int shift = 24; shift >= 0; shift -= 8) {
        int need = sh_need;
        unsigned pref = sh_pref;
        hist[tid] = 0;
        __syncthreads();
        unsigned hmask = (shift == 24) ? 0u : (0xFFFFFFFFu << (shift + 8));
        for (int j = tid; j < 2048; j += 256) {
            unsigned ky = keys[j];
            if ((ky & hmask) == pref)
                atomicAdd(&hist[(ky >> shift) & 255], 1);
        }
        __syncthreads();
        // inclusive suffix sum: suf[d] = sum_{d'>=d} hist[d']
        suf[tid] = hist[tid];
        __syncthreads();
#pragma unroll
        for (int st = 1; st < 256; st <<= 1) {
            int add = (tid + st < 256) ? suf[tid + st] : 0;
            __syncthreads();
            suf[tid] += add;
            __syncthreads();
        }
        // unique digit d with suffix_excl(d) < need <= suffix_incl(d)
        if (suf[tid] >= need && suf[tid] - hist[tid] < need) {
            sh_pref = pref | ((unsigned)tid << shift);
            sh_need = need - (suf[tid] - hist[tid]);
        }
        __syncthreads();
    }
    unsigned thr = sh_pref;
    for (int j = tid; j < 2048; j += 256)
        maskf[bh * 2048 + j] = (keys[j] >= thr) ? 1.0f : 0.0f;
}

// PV with swapped-operand QK^T, in-register P, block-level LDS staging of
// frag-major K/V in 64-key chunks. XCD-chunked remap.
__global__ __launch_bounds__(256) void attn_av(
    const short* __restrict__ Qhi, const short* __restrict__ Kf,
    const short* __restrict__ Vf, const float* __restrict__ rowsum,
    unsigned short* __restrict__ concat)
{
    __shared__ __align__(16) short KA[8192];   // [0,4096): K 64 keys, [4096,8192): V
    __shared__ __align__(16) short KB[8192];
    int lin = blockIdx.x + (blockIdx.y << 4);          // [0,512)
    int tile = (lin & 7) * 64 + (lin >> 3);
    int bxx = tile & 15, bh = tile >> 4;
    int tid = threadIdx.x;
    int w = tid >> 6, lane = tid & 63;
    int lq = lane & 31, hi = lane >> 5;
    int qb = bxx * 128 + w * 32;
    const short* Qb = Qhi + (size_t)bh * 131072 + (size_t)(qb >> 5) * 2048;
    const short* Kg = Kf  + (size_t)bh * 131072;
    const short* Vg = Vf  + (size_t)bh * 131072;

    short8 qf[4];
#pragma unroll
    for (int d = 0; d < 4; d++)
        qf[d] = *(const short8*)(Qb + (size_t)(d*2 + hi) * 256 + lq * 8);

    f32x16 o0, o1;
#pragma unroll
    for (int i = 0; i < 16; i++) { o0[i] = 0.f; o1[i] = 0.f; }

    auto STAGE = [&](short* B, int c) {     // c in [0,32): 64-key chunk
        const short* Kc = Kg + (size_t)c * 4096;
        const short* Vc = Vg + (size_t)c * 4096;
        __builtin_amdgcn_global_load_lds(AS1(Kc + tid*8),        AS3(B + w*512), 16, 0, 0);
        __builtin_amdgcn_global_load_lds(AS1(Kc + 2048 + tid*8), AS3(B + 2048 + w*512), 16, 0, 0);
        __builtin_amdgcn_global_load_lds(AS1(Vc + tid*8),        AS3(B + 4096 + w*512), 16, 0, 0);
        __builtin_amdgcn_global_load_lds(AS1(Vc + 2048 + tid*8), AS3(B + 4096 + 2048 + w*512), 16, 0, 0);
    };

    // one 32-key half: S^T -> exp -> pack -> PV (same op order as before)
    auto half_comp = [&](const short* Bk, const short* Bv) {
        short8 kf_[4], vf_[4];
#pragma unroll
        for (int d = 0; d < 4; d++)
            kf_[d] = *(const short8*)(Bk + (d*2 + hi)*256 + lq*8);
#pragma unroll
        for (int ks = 0; ks < 2; ks++)
#pragma unroll
            for (int nt = 0; nt < 2; nt++)
                vf_[ks*2+nt] = *(const short8*)(Bv + ((ks*2+nt)*2 + hi)*256 + lq*8);

        f32x16 s;
#pragma unroll
        for (int i = 0; i < 16; i++) s[i] = 0.f;
        s = MFMA32(kf_[0], qf[0], s);
        s = MFMA32(kf_[1], qf[1], s);
        s = MFMA32(kf_[2], qf[2], s);
        s = MFMA32(kf_[3], qf[3], s);

        float p[16];
#pragma unroll
        for (int i = 0; i < 16; i++) p[i] = PEXP(s[i]);

        short8 pa[2];
#pragma unroll
        for (int ks = 0; ks < 2; ks++) {
            unsigned w0, w1, w2, w3;
            int o8 = ks * 8;
            asm("v_cvt_pk_bf16_f32 %0, %1, %2" : "=v"(w0) : "v"(p[o8+0]), "v"(p[o8+1]));
            asm("v_cvt_pk_bf16_f32 %0, %1, %2" : "=v"(w1) : "v"(p[o8+2]), "v"(p[o8+3]));
            asm("v_cvt_pk_bf16_f32 %0, %1, %2" : "=v"(w2) : "v"(p[o8+4]), "v"(p[o8+5]));
            asm("v_cvt_pk_bf16_f32 %0, %1, %2" : "=v"(w3) : "v"(p[o8+6]), "v"(p[o8+7]));
            asm("v_permlane32_swap_b32 %0, %1" : "+v"(w0), "+v"(w2));
            asm("v_permlane32_swap_b32 %0, %1" : "+v"(w1), "+v"(w3));
            u32x4 pw = { w0, w1, w2, w3 };
            pa[ks] = __builtin_bit_cast(short8, pw);
        }

        o0 = MFMA32(pa[0], vf_[0], o0);
        o1 = MFMA32(pa[0], vf_[1], o1);
        o0 = MFMA32(pa[1], vf_[2], o0);
        o1 = MFMA32(pa[1], vf_[3], o1);
    };
    auto comp = [&](const short* B) {
        half_comp(B, B + 4096);                 // keys [c*64, c*64+32)
        half_comp(B + 2048, B + 4096 + 2048);   // keys [c*64+32, c*64+64)
    };

    STAGE(KA, 0);
    __syncthreads();
    for (int c = 0; c < 32; c += 2) {
        STAGE(KB, c + 1);           // next chunk's loads fly under compute
        comp(KA);
        __syncthreads();            // publishes KB, guards KA reuse
        if (c + 2 < 32) STAGE(KA, c + 2);
        comp(KB);
        __syncthreads();
    }

    int b_ = bh >> 4, h = bh & 15;
#pragma unroll
    for (int r = 0; r < 16; r++) {
        int crow = (r & 3) + 8*(r >> 2) + 4*hi;
        float inv = 1.0f / rowsum[bh * 2048 + qb + crow];
        size_t base = ((size_t)(b_*2048 + qb + crow)) * 1024 + h*64;
        concat[base + lq]      = f2bf(o0[r] * inv);
        concat[base + 32 + lq] = f2bf(o1[r] * inv);
    }
}

extern "C" void kernel_launch(void* const* d_in, const int* in_sizes, int n_in,
                              void* d_out, int out_size, void* d_ws, size_t ws_size,
                              hipStream_t stream)
{
    const float* q  = (const float*)d_in[0];
    const float* k  = (const float*)d_in[1];
    const float* v  = (const float*)d_in[2];
    const float* Wq = (const float*)d_in[3];
    const float* bq = (const float*)d_in[4];
    const float* Wk = (const float*)d_in[5];
    const float* bk = (const float*)d_in[6];
    const float* Wv = (const float*)d_in[7];
    const float* bv = (const float*)d_in[8];
    const float* Wo = (const float*)d_in[9];
    const float* bo = (const float*)d_in[10];

    char* ws = (char*)d_ws;
    size_t off = 0;
    auto alloc = [&](size_t bytes) -> void* {
        void* p = ws + off;
        off += (bytes + 255) & ~(size_t)255;
        return p;
    };
    const size_t ASZ = (size_t)4096 * 1024 * 2;   // 8.4 MB bf16 activation
    const size_t WSZ = (size_t)1024 * 1024 * 2;   // 2 MB bf16 weight
    unsigned short* qh_ = (unsigned short*)alloc(ASZ);
    unsigned short* ql_ = (unsigned short*)alloc(ASZ);
    unsigned short* kh_ = (unsigned short*)alloc(ASZ);
    unsigned short* kl_ = (unsigned short*)alloc(ASZ);
    unsigned short* vh_ = (unsigned short*)alloc(ASZ);
    unsigned short* wqh = (unsigned short*)alloc(WSZ);
    unsigned short* wql = (unsigned short*)alloc(WSZ);
    unsigned short* wkh = (unsigned short*)alloc(WSZ);
    unsigned short* wkl = (unsigned short*)alloc(WSZ);
    unsigned short* wvh = (unsigned short*)alloc(WSZ);
    unsigned short* woh = (unsigned short*)alloc(WSZ);
    unsigned short* wol = (unsigned short*)alloc(WSZ);
    short* Qhi = (short*)alloc(ASZ);   // frag-major
    short* Qlo = (short*)alloc(ASZ);   // frag-major
    short* Khi = (short*)alloc(ASZ);   // frag-major
    short* Klo = (short*)alloc(ASZ);   // frag-major
    short* Vt  = (short*)alloc(ASZ);   // frag-major
    float* rowsum = (float*)alloc((size_t)32 * 2048 * 4);
    float* colsum = (float*)alloc((size_t)32 * 2048 * 4);   // contiguous after rowsum
    float* maskf  = (float*)alloc((size_t)32 * 2048 * 4);
    unsigned short* concat = (unsigned short*)alloc(ASZ);
    // total ~110 MB (known-safe)

    dim3 blk(256);

    cvt_all<<<dim3(16512), blk, 0, stream>>>(
        q, k, v, Wq, Wk, Wv, Wo,
        qh_, ql_, kh_, kl_, vh_, wqh, wql, wkh, wkl, wvh, woh, wol,
        rowsum /* zbuf: zeros rowsum+colsum (contiguous) */);

    gemm_qkv<<<dim3(16, 32, 2), blk, 0, stream>>>(
        (const short*)qh_, (const short*)ql_, (const short*)kh_, (const short*)kl_,
        (const short*)wqh, (const short*)wql, (const short*)wkh, (const short*)wkl,
        bq, bk,
        (unsigned short*)Qhi, (unsigned short*)Qlo,
        (unsigned short*)Khi, (unsigned short*)Klo);

    attn_rowsum<<<dim3(8, 4, 32), blk, 0, stream>>>(Qhi, Khi, rowsum);
    attn_colsum<<<dim3(8, 4, 32), blk, 0, stream>>>(Qhi, Qlo, Khi, Klo, rowsum, colsum);
    topk_mask  <<<dim3(32),   blk, 0, stream>>>(colsum, maskf);

    gemm_v<<<dim3(16, 32), blk, 0, stream>>>(
        (const short*)vh_, (const short*)wvh, bv, maskf, (unsigned short*)Vt);

    attn_av    <<<dim3(16, 32), blk, 0, stream>>>(Qhi, Khi, Vt, rowsum, concat);

    gemm_out<<<dim3(16, 32), blk, 0, stream>>>((const short*)concat,
        (const short*)woh, (const short*)wol, bo, (float*)d_out);
}